// Round 1
// baseline (176.325 us; speedup 1.0000x reference)
//
#include <hip/hip_runtime.h>
#include <hip/hip_bf16.h>

typedef unsigned short u16;
typedef __attribute__((ext_vector_type(8))) short bf16x8;   // 8 bf16 in 4 VGPRs (guide-verified operand type)
typedef __attribute__((ext_vector_type(8))) u16 u16x8;
typedef __attribute__((ext_vector_type(4))) u16 u16x4;
typedef __attribute__((ext_vector_type(4))) float f32x4;

typedef const __attribute__((address_space(1))) void* gas1_t;
typedef __attribute__((address_space(3))) void* las3_t;

#define MFMA16(a, b, c) __builtin_amdgcn_mfma_f32_16x16x32_bf16((a), (b), (c), 0, 0, 0)

static constexpr int BB = 4, SS = 1024, DD = 1024, HH = 16;

static __device__ __forceinline__ u16 f2b(float x) {
  union { __hip_bfloat16 h; u16 u; } cv;
  cv.h = __float2bfloat16(x);  // RTN-even
  return cv.u;
}

// ---------------- fp32 -> bf16 conversion (vectorized) ----------------
__global__ __launch_bounds__(256) void cvt_kernel(const float* __restrict__ src,
                                                  u16* __restrict__ dst, int n) {
  int i = (blockIdx.x * 256 + threadIdx.x) * 4;
  if (i >= n) return;
  float4 v = *(const float4*)(src + i);
  u16x4 r = { f2b(v.x), f2b(v.y), f2b(v.z), f2b(v.w) };
  *(u16x4*)(dst + i) = r;
}

// ---------------- GEMM: C[M,N] = A[M,K] * W[N,K]^T  (m97-style 128x128 tile) ----------------
// grid: (N/128, M/128, Z); z selects A/W/C via element strides.
template<typename OT>
__global__ __launch_bounds__(256) void gemm_bt(
    const u16* __restrict__ Abase, const u16* __restrict__ Wbase, OT* __restrict__ Cbase,
    int N, int K, size_t sA, size_t sW, size_t sC) {
  const u16* A = Abase + (size_t)blockIdx.z * sA;
  const u16* W = Wbase + (size_t)blockIdx.z * sW;
  OT* C = Cbase + (size_t)blockIdx.z * sC;

  __shared__ __align__(16) u16 As[128 * 32];
  __shared__ __align__(16) u16 Bs[128 * 32];

  const int tid = threadIdx.x;
  const int lane = tid & 63;
  const int wid = tid >> 6;
  const int g = lane >> 4;        // 4 lane-groups of 16
  const int li = lane & 15;
  const int brow = blockIdx.y * 128;
  const int bcol = blockIdx.x * 128;
  const int wr = (wid >> 1) * 64;  // wave's 64-row strip
  const int wc = (wid & 1) * 64;   // wave's 64-col strip

  const int srow = tid >> 2;        // staging: row within tile
  const int scol = (tid & 3) * 8;   // staging: col (elements)

  f32x4 acc[4][4] = {};

  for (int k0 = 0; k0 < K; k0 += 32) {
    // ---- stage A/B tiles (128x32 bf16 each) via async global->LDS, 16B/lane ----
#pragma unroll
    for (int c = 0; c < 2; ++c) {
      const u16* ga = A + (size_t)(brow + srow + c * 64) * K + k0 + scol;
      const u16* gw = W + (size_t)(bcol + srow + c * 64) * K + k0 + scol;
      __builtin_amdgcn_global_load_lds((gas1_t)(const void*)ga,
                                       (las3_t)(void*)(As + wid * 512 + c * 2048), 16, 0, 0);
      __builtin_amdgcn_global_load_lds((gas1_t)(const void*)gw,
                                       (las3_t)(void*)(Bs + wid * 512 + c * 2048), 16, 0, 0);
    }
    __syncthreads();

    // ---- fragments + MFMA ----
    bf16x8 a[4], b[4];
#pragma unroll
    for (int m = 0; m < 4; ++m)
      a[m] = *(const bf16x8*)&As[(wr + m * 16 + li) * 32 + g * 8];
#pragma unroll
    for (int n = 0; n < 4; ++n)
      b[n] = *(const bf16x8*)&Bs[(wc + n * 16 + li) * 32 + g * 8];
#pragma unroll
    for (int m = 0; m < 4; ++m)
#pragma unroll
      for (int n = 0; n < 4; ++n)
        acc[m][n] = MFMA16(a[m], b[n], acc[m][n]);
    __syncthreads();
  }

  // ---- epilogue: C layout col=lane&15, row=(lane>>4)*4+j ----
#pragma unroll
  for (int m = 0; m < 4; ++m) {
#pragma unroll
    for (int n = 0; n < 4; ++n) {
#pragma unroll
      for (int j = 0; j < 4; ++j) {
        int r = brow + wr + m * 16 + g * 4 + j;
        int c = bcol + wc + n * 16 + li;
        if constexpr (sizeof(OT) == 2) {
          C[(size_t)r * N + c] = (OT)f2b(acc[m][n][j]);
        } else {
          C[(size_t)r * N + c] = acc[m][n][j];
        }
      }
    }
  }
}

// ---------------- V transpose: V[b*S+s][h*64+dv] -> Vt[((b*H+h)*64+dv)*S + s] ----------------
__global__ __launch_bounds__(256) void transpose_v(const u16* __restrict__ V, u16* __restrict__ Vt) {
  __shared__ __align__(16) u16 t[64][72];
  const int s0 = blockIdx.x * 64, h = blockIdx.y, b = blockIdx.z;
  const int tid = threadIdx.x;
#pragma unroll
  for (int it = 0; it < 2; ++it) {
    int slot = tid + it * 256;
    int r = slot >> 3, seg = slot & 7;
    *(u16x8*)&t[r][seg * 8] = *(const u16x8*)&V[(size_t)(b * SS + s0 + r) * DD + h * 64 + seg * 8];
  }
  __syncthreads();
#pragma unroll
  for (int it = 0; it < 2; ++it) {
    int slot = tid + it * 256;
    int dv = slot >> 3, seg = slot & 7;
    u16x8 v;
#pragma unroll
    for (int i = 0; i < 8; ++i) v[i] = t[seg * 8 + i][dv];
    *(u16x8*)&Vt[(size_t)((b * HH + h) * 64 + dv) * SS + s0 + seg * 8] = v;
  }
}

// ---------------- fused flash attention ----------------
// grid: (S/64, H, B); block: 256 threads (4 waves), each wave owns 16 q-rows.
__global__ __launch_bounds__(256) void attn_kernel(
    const u16* __restrict__ Q, const u16* __restrict__ K, const u16* __restrict__ Vt,
    const float* __restrict__ bias, u16* __restrict__ O) {
  __shared__ __align__(16) u16 Qs[64][72];
  __shared__ __align__(16) u16 Ks[64][72];
  __shared__ __align__(16) u16 Vs[64][72];  // Vs[dv][key]
  __shared__ __align__(16) u16 Ps[64][72];  // per-wave disjoint 16-row strips

  const int tid = threadIdx.x;
  const int lane = tid & 63;
  const int wid = tid >> 6;
  const int g = lane >> 4;
  const int li = lane & 15;
  const int qt = blockIdx.x, h = blockIdx.y, b = blockIdx.z;
  const int q0 = qt * 64;

  // stage Q tile once
#pragma unroll
  for (int it = 0; it < 2; ++it) {
    int slot = tid + it * 256;
    int r = slot >> 3, seg = slot & 7;
    *(u16x8*)&Qs[r][seg * 8] = *(const u16x8*)&Q[(size_t)(b * SS + q0 + r) * DD + h * 64 + seg * 8];
  }
  __syncthreads();
  bf16x8 qf[2];
  qf[0] = *(const bf16x8*)&Qs[wid * 16 + li][g * 8];
  qf[1] = *(const bf16x8*)&Qs[wid * 16 + li][32 + g * 8];

  f32x4 o[4] = {};
  float mrow[4] = {-1e30f, -1e30f, -1e30f, -1e30f};
  float lrow[4] = {0.f, 0.f, 0.f, 0.f};

  for (int kt = 0; kt < SS / 64; ++kt) {
    const int k0 = kt * 64;
    __syncthreads();  // all waves done with previous K/V tiles
#pragma unroll
    for (int it = 0; it < 2; ++it) {
      int slot = tid + it * 256;
      int r = slot >> 3, seg = slot & 7;
      *(u16x8*)&Ks[r][seg * 8] = *(const u16x8*)&K[(size_t)(b * SS + k0 + r) * DD + h * 64 + seg * 8];
      *(u16x8*)&Vs[r][seg * 8] = *(const u16x8*)&Vt[(size_t)((b * HH + h) * 64 + r) * SS + k0 + seg * 8];
    }
    __syncthreads();

    // ---- S = Q K^T (this wave's 16 q-rows x 64 keys), scale + bias in fp32 ----
    f32x4 s[4];
#pragma unroll
    for (int n = 0; n < 4; ++n) {
      bf16x8 kf0 = *(const bf16x8*)&Ks[n * 16 + li][g * 8];
      bf16x8 kf1 = *(const bf16x8*)&Ks[n * 16 + li][32 + g * 8];
      f32x4 z = {};
      z = MFMA16(qf[0], kf0, z);
      z = MFMA16(qf[1], kf1, z);
      s[n] = z;
    }
#pragma unroll
    for (int n = 0; n < 4; ++n) {
#pragma unroll
      for (int j = 0; j < 4; ++j) {
        int qq = q0 + wid * 16 + g * 4 + j;
        int kk = k0 + n * 16 + li;
        s[n][j] = s[n][j] * 0.03125f + bias[(size_t)(b * SS + qq) * SS + kk];  // D^-0.5 = 1/32
      }
    }

    // ---- online softmax (rows live in 16-lane groups; shfl-reduce) ----
    float f[4];
#pragma unroll
    for (int j = 0; j < 4; ++j) {
      float mx = fmaxf(fmaxf(s[0][j], s[1][j]), fmaxf(s[2][j], s[3][j]));
      mx = fmaxf(mx, __shfl_xor(mx, 1));
      mx = fmaxf(mx, __shfl_xor(mx, 2));
      mx = fmaxf(mx, __shfl_xor(mx, 4));
      mx = fmaxf(mx, __shfl_xor(mx, 8));
      float mnew = fmaxf(mrow[j], mx);
      f[j] = __expf(mrow[j] - mnew);
      mrow[j] = mnew;
      float sum = 0.f;
#pragma unroll
      for (int n = 0; n < 4; ++n) {
        float p = __expf(s[n][j] - mnew);
        s[n][j] = p;
        sum += p;
      }
      sum += __shfl_xor(sum, 1);
      sum += __shfl_xor(sum, 2);
      sum += __shfl_xor(sum, 4);
      sum += __shfl_xor(sum, 8);
      lrow[j] = lrow[j] * f[j] + sum;
    }

    // ---- P -> LDS (bf16), rescale accumulator ----
#pragma unroll
    for (int n = 0; n < 4; ++n)
#pragma unroll
      for (int j = 0; j < 4; ++j)
        Ps[wid * 16 + g * 4 + j][n * 16 + li] = f2b(s[n][j]);
#pragma unroll
    for (int n = 0; n < 4; ++n)
#pragma unroll
      for (int j = 0; j < 4; ++j)
        o[n][j] *= f[j];

    // ---- PV: o += P @ V  (same-wave LDS write->read, DS pipe is in-order) ----
#pragma unroll
    for (int kk = 0; kk < 2; ++kk) {
      bf16x8 pf = *(const bf16x8*)&Ps[wid * 16 + li][kk * 32 + g * 8];
#pragma unroll
      for (int n = 0; n < 4; ++n) {
        bf16x8 vf = *(const bf16x8*)&Vs[n * 16 + li][kk * 32 + g * 8];
        o[n] = MFMA16(pf, vf, o[n]);
      }
    }
  }

  // ---- normalize + write ----
#pragma unroll
  for (int n = 0; n < 4; ++n) {
    float inv;
#pragma unroll
    for (int j = 0; j < 4; ++j) {
      inv = 1.0f / lrow[j];
      int qq = q0 + wid * 16 + g * 4 + j;
      O[(size_t)(b * SS + qq) * DD + h * 64 + n * 16 + li] = f2b(o[n][j] * inv);
    }
  }
}

// ---------------- host launch ----------------
extern "C" void kernel_launch(void* const* d_in, const int* in_sizes, int n_in,
                              void* d_out, int out_size, void* d_ws, size_t ws_size,
                              hipStream_t stream) {
  const float* queries = (const float*)d_in[0];
  const float* keys    = (const float*)d_in[1];
  const float* values  = (const float*)d_in[2];
  const float* bias    = (const float*)d_in[3];
  const float* Wq      = (const float*)d_in[4];
  const float* Wk      = (const float*)d_in[5];
  const float* Wv      = (const float*)d_in[6];
  const float* Wp      = (const float*)d_in[7];
  float* out = (float*)d_out;

  char* ws = (char*)d_ws;
  const size_t MB = 1024 * 1024;
  u16* qb  = (u16*)(ws + 0 * MB);
  u16* kb  = (u16*)(ws + 8 * MB);
  u16* vb  = (u16*)(ws + 16 * MB);
  u16* wqb = (u16*)(ws + 24 * MB);
  u16* wkb = (u16*)(ws + 26 * MB);
  u16* wvb = (u16*)(ws + 28 * MB);
  u16* wpb = (u16*)(ws + 30 * MB);
  u16* Qb  = (u16*)(ws + 32 * MB);
  u16* Kb  = (u16*)(ws + 40 * MB);
  u16* Vb  = (u16*)(ws + 48 * MB);
  u16* Vtb = (u16*)(ws + 56 * MB);
  u16* Ob  = (u16*)(ws + 0 * MB);  // reuse qb region (dead after projections)

  const int nAct = BB * SS * DD;       // 4M
  const int nW = DD * DD;              // 1M

  cvt_kernel<<<dim3(nAct / 1024), dim3(256), 0, stream>>>(queries, qb, nAct);
  cvt_kernel<<<dim3(nAct / 1024), dim3(256), 0, stream>>>(keys, kb, nAct);
  cvt_kernel<<<dim3(nAct / 1024), dim3(256), 0, stream>>>(values, vb, nAct);
  cvt_kernel<<<dim3(nW / 1024), dim3(256), 0, stream>>>(Wq, wqb, nW);
  cvt_kernel<<<dim3(nW / 1024), dim3(256), 0, stream>>>(Wk, wkb, nW);
  cvt_kernel<<<dim3(nW / 1024), dim3(256), 0, stream>>>(Wv, wvb, nW);
  cvt_kernel<<<dim3(nW / 1024), dim3(256), 0, stream>>>(Wp, wpb, nW);

  // fused QKV projections: z=0 Q, z=1 K, z=2 V
  gemm_bt<u16><<<dim3(8, 32, 3), dim3(256), 0, stream>>>(
      qb, wqb, Qb, DD, DD, (size_t)nAct, (size_t)nW, (size_t)nAct);

  transpose_v<<<dim3(16, 16, 4), dim3(256), 0, stream>>>(Vb, Vtb);

  attn_kernel<<<dim3(16, 16, 4), dim3(256), 0, stream>>>(Qb, Kb, Vtb, bias, Ob);

  // output projection (fp32 out)
  gemm_bt<float><<<dim3(8, 32, 1), dim3(256), 0, stream>>>(
      Ob, wpb, out, DD, DD, 0, 0, 0);
}

// Round 2
// 139.767 us; speedup vs baseline: 1.2616x; 1.2616x over previous
//
#include <hip/hip_runtime.h>
#include <hip/hip_bf16.h>

typedef unsigned short u16;
typedef unsigned int u32;
typedef __attribute__((ext_vector_type(8))) short bf16x8;   // 8 bf16 (4 VGPRs)
typedef __attribute__((ext_vector_type(8))) u16 u16x8;
typedef __attribute__((ext_vector_type(4))) u16 u16x4;
typedef __attribute__((ext_vector_type(4))) u32 u32x4;
typedef __attribute__((ext_vector_type(4))) float f32x4;
typedef __attribute__((ext_vector_type(16))) float f32x16;

typedef const __attribute__((address_space(1))) void* gas1_t;
typedef __attribute__((address_space(3))) void* las3_t;

#define MFMA16(a,b,c) __builtin_amdgcn_mfma_f32_16x16x32_bf16((a),(b),(c),0,0,0)
#define MFMA32(a,b,c) __builtin_amdgcn_mfma_f32_32x32x16_bf16((a),(b),(c),0,0,0)

static constexpr int BB = 4, SS = 1024, DD = 1024, HH = 16;

static __device__ __forceinline__ u16 f2b(float x) {
  union { __hip_bfloat16 h; u16 u; } cv;
  cv.h = __float2bfloat16(x);
  return cv.u;
}
static __device__ __forceinline__ u32 pk2(float a, float b) {
  return (u32)f2b(a) | ((u32)f2b(b) << 16);
}

// ---------------- fused fp32 -> bf16 conversion (one launch for all 7 tensors) ----------------
__global__ __launch_bounds__(256) void cvt_all(
    const float* __restrict__ q, const float* __restrict__ k, const float* __restrict__ v,
    const float* __restrict__ wq_, const float* __restrict__ wk_, const float* __restrict__ wv_,
    const float* __restrict__ wp_,
    u16* __restrict__ qb, u16* __restrict__ kb, u16* __restrict__ vb,
    u16* __restrict__ wqb, u16* __restrict__ wkb, u16* __restrict__ wvb, u16* __restrict__ wpb) {
  int bid = blockIdx.x;
  const float* s; u16* d; int off;
  if      (bid < 4096)  { s = q;   d = qb;  off = bid; }
  else if (bid < 8192)  { s = k;   d = kb;  off = bid - 4096; }
  else if (bid < 12288) { s = v;   d = vb;  off = bid - 8192; }
  else if (bid < 13312) { s = wq_; d = wqb; off = bid - 12288; }
  else if (bid < 14336) { s = wk_; d = wkb; off = bid - 13312; }
  else if (bid < 15360) { s = wv_; d = wvb; off = bid - 14336; }
  else                  { s = wp_; d = wpb; off = bid - 15360; }
  int i = (off * 256 + threadIdx.x) * 4;
  float4 val = *(const float4*)(s + i);
  u16x4 r = { f2b(val.x), f2b(val.y), f2b(val.z), f2b(val.w) };
  *(u16x4*)(d + i) = r;
}

// ---------------- GEMM: C[M,N] = A[M,K] * W[N,K]^T  (m97-style 128x128 tile) ----------------
template<typename OT>
__global__ __launch_bounds__(256) void gemm_bt(
    const u16* __restrict__ Abase, const u16* __restrict__ Wbase, OT* __restrict__ Cbase,
    int N, int K, size_t sA, size_t sW, size_t sC) {
  const u16* A = Abase + (size_t)blockIdx.z * sA;
  const u16* W = Wbase + (size_t)blockIdx.z * sW;
  OT* C = Cbase + (size_t)blockIdx.z * sC;

  __shared__ __align__(16) u16 As[128 * 32];
  __shared__ __align__(16) u16 Bs[128 * 32];

  const int tid = threadIdx.x;
  const int lane = tid & 63;
  const int wid = tid >> 6;
  const int g = lane >> 4;
  const int li = lane & 15;
  const int brow = blockIdx.y * 128;
  const int bcol = blockIdx.x * 128;
  const int wr = (wid >> 1) * 64;
  const int wc = (wid & 1) * 64;

  const int srow = tid >> 2;
  const int scol = (tid & 3) * 8;

  f32x4 acc[4][4] = {};

  for (int k0 = 0; k0 < K; k0 += 32) {
#pragma unroll
    for (int c = 0; c < 2; ++c) {
      const u16* ga = A + (size_t)(brow + srow + c * 64) * K + k0 + scol;
      const u16* gw = W + (size_t)(bcol + srow + c * 64) * K + k0 + scol;
      __builtin_amdgcn_global_load_lds((gas1_t)(const void*)ga,
                                       (las3_t)(void*)(As + wid * 512 + c * 2048), 16, 0, 0);
      __builtin_amdgcn_global_load_lds((gas1_t)(const void*)gw,
                                       (las3_t)(void*)(Bs + wid * 512 + c * 2048), 16, 0, 0);
    }
    __syncthreads();

    bf16x8 a[4], b[4];
#pragma unroll
    for (int m = 0; m < 4; ++m)
      a[m] = *(const bf16x8*)&As[(wr + m * 16 + li) * 32 + g * 8];
#pragma unroll
    for (int n = 0; n < 4; ++n)
      b[n] = *(const bf16x8*)&Bs[(wc + n * 16 + li) * 32 + g * 8];
#pragma unroll
    for (int m = 0; m < 4; ++m)
#pragma unroll
      for (int n = 0; n < 4; ++n)
        acc[m][n] = MFMA16(a[m], b[n], acc[m][n]);
    __syncthreads();
  }

#pragma unroll
  for (int m = 0; m < 4; ++m)
#pragma unroll
    for (int n = 0; n < 4; ++n)
#pragma unroll
      for (int j = 0; j < 4; ++j) {
        int r = brow + wr + m * 16 + g * 4 + j;
        int c = bcol + wc + n * 16 + li;
        if constexpr (sizeof(OT) == 2) C[(size_t)r * N + c] = (OT)f2b(acc[m][n][j]);
        else                           C[(size_t)r * N + c] = acc[m][n][j];
      }
}

// ---------------- V transpose: V[b*S+s][h*64+dv] -> Vt[((b*H+h)*64+dv)*S + s] ----------------
__global__ __launch_bounds__(256) void transpose_v(const u16* __restrict__ V, u16* __restrict__ Vt) {
  __shared__ __align__(16) u16 t[64][72];
  const int s0 = blockIdx.x * 64, h = blockIdx.y, b = blockIdx.z;
  const int tid = threadIdx.x;
#pragma unroll
  for (int it = 0; it < 2; ++it) {
    int slot = tid + it * 256;
    int r = slot >> 3, seg = slot & 7;
    *(u16x8*)&t[r][seg * 8] = *(const u16x8*)&V[(size_t)(b * SS + s0 + r) * DD + h * 64 + seg * 8];
  }
  __syncthreads();
#pragma unroll
  for (int it = 0; it < 2; ++it) {
    int slot = tid + it * 256;
    int dv = slot >> 3, seg = slot & 7;
    u16x8 v;
#pragma unroll
    for (int i = 0; i < 8; ++i) v[i] = t[seg * 8 + i][dv];
    *(u16x8*)&Vt[(size_t)((b * HH + h) * 64 + dv) * SS + s0 + seg * 8] = v;
  }
}

// ---------------- fused flash attention (m214-style, 32x32 MFMA, swapped QK^T) ----------------
// grid: (S/128, H, B); block 256 = 4 waves, each wave owns 32 q-rows (q = lane&31).
__global__ __launch_bounds__(256) void attn_kernel(
    const u16* __restrict__ Q, const u16* __restrict__ K, const u16* __restrict__ Vt,
    const float* __restrict__ bias, u16* __restrict__ O) {
  __shared__ __align__(16) u16 kbuf[2][64 * 64];   // [k][d], XOR-swizzled
  __shared__ __align__(16) u16 vbuf[2][64 * 64];   // [dv][k], XOR-swizzled
  __shared__ float Lf[4][32];

  const int tid = threadIdx.x;
  const int lane = tid & 63;
  const int wq = tid >> 6;
  const int hi = lane >> 5;
  const int ln = lane & 31;
  const u32 swz = (u32)(ln & 7) << 4;
  const int h = blockIdx.y, b = blockIdx.z;
  const int q0 = blockIdx.x * 128;
  const int qrow = q0 + wq * 32 + ln;       // this lane's softmax row

  // Q B-fragments: lane holds Q[qrow][d = dstep*16 + hi*8 + e]
  bf16x8 qf[4];
  {
    const u16* qp = Q + (size_t)(b * SS + qrow) * DD + h * 64 + hi * 8;
#pragma unroll
    for (int d = 0; d < 4; ++d) qf[d] = *(const bf16x8*)(qp + d * 16);
  }

  // staging map: thread -> (row sr, 32B chunk)
  const int sr = tid >> 2;
  const int scb = (tid & 3) * 32;                   // byte offset within 128B row
  const u16* kg = K + (size_t)(b * SS + sr) * DD + h * 64 + scb / 2;
  const u16* vg = Vt + (size_t)((b * HH + h) * 64 + sr) * SS + scb / 2;
  const u32 wa0 = (u32)sr * 128 + (((u32)scb) ^ ((u32)(sr & 7) << 4));
  const u32 wa1 = (u32)sr * 128 + (((u32)scb + 16) ^ ((u32)(sr & 7) << 4));

  u16x8 kr0, kr1, vr0, vr1;
  kr0 = *(const u16x8*)(kg + 0);
  kr1 = *(const u16x8*)(kg + 8);
  vr0 = *(const u16x8*)(vg + 0);
  vr1 = *(const u16x8*)(vg + 8);
  *(u16x8*)((char*)kbuf[0] + wa0) = kr0;
  *(u16x8*)((char*)kbuf[0] + wa1) = kr1;
  *(u16x8*)((char*)vbuf[0] + wa0) = vr0;
  *(u16x8*)((char*)vbuf[0] + wa1) = vr1;
  __syncthreads();

  f32x16 o0 = {}, o1 = {};
  float m = -1e30f, lsum = 0.f;
  int cur = 0;

  for (int kt = 0; kt < 16; ++kt) {
    // T14: issue next-tile global loads early (consumed by LDS writes after compute)
    if (kt < 15) {
      const size_t k1 = (size_t)(kt + 1) * 64;
      kr0 = *(const u16x8*)(kg + k1 * DD + 0);
      kr1 = *(const u16x8*)(kg + k1 * DD + 8);
      vr0 = *(const u16x8*)(vg + k1 + 0);
      vr1 = *(const u16x8*)(vg + k1 + 8);
    }

    // bias: fragment-aligned float4 gathers (row = qrow, lane-local)
    f32x4 bb[2][4];
    {
      const float* bp = bias + (size_t)(b * SS + qrow) * SS + kt * 64 + hi * 4;
#pragma unroll
      for (int kb = 0; kb < 2; ++kb)
#pragma unroll
        for (int rq = 0; rq < 4; ++rq)
          bb[kb][rq] = *(const f32x4*)(bp + kb * 32 + rq * 8);
    }

    // swapped QK^T: s = mfma(K, Q) -> C: col = q = ln, row(k) = (r&3)+8*(r>>2)+4*hi (+32*kb)
    const char* kb_base = (const char*)kbuf[cur];
    f32x16 s[2];
#pragma unroll
    for (int kb = 0; kb < 2; ++kb) {
      f32x16 acc = {};
#pragma unroll
      for (int d = 0; d < 4; ++d) {
        bf16x8 kf = *(const bf16x8*)(kb_base + (kb * 32 + ln) * 128 + (((u32)(d * 32 + hi * 16)) ^ swz));
        acc = MFMA32(kf, qf[d], acc);
      }
      s[kb] = acc;
    }
    // scale (D^-0.5 = 1/32) + bias in fp32
#pragma unroll
    for (int kb = 0; kb < 2; ++kb)
#pragma unroll
      for (int rq = 0; rq < 4; ++rq)
#pragma unroll
        for (int c = 0; c < 4; ++c)
          s[kb][rq * 4 + c] = fmaf(s[kb][rq * 4 + c], 0.03125f, bb[kb][rq][c]);

    // in-register row softmax (row is lane-local; only cross-hi shuffle needed)
    float mt = -1e30f;
#pragma unroll
    for (int r = 0; r < 16; ++r) { mt = fmaxf(mt, s[0][r]); mt = fmaxf(mt, s[1][r]); }
    mt = fmaxf(mt, __shfl_xor(mt, 32));

    bool resc = false;
    float fsc = 1.f;
    if (kt == 0) {
      m = mt;
    } else if (__any(mt > m + 8.f)) {   // T13 defer-max
      float mn = fmaxf(m, mt);
      fsc = __expf(m - mn);
      m = mn;
      resc = true;
    }

    float rs = 0.f;
    u32 w[2][8];
#pragma unroll
    for (int kb = 0; kb < 2; ++kb)
#pragma unroll
      for (int t = 0; t < 8; ++t) {
        float p0 = __expf(s[kb][2 * t] - m);
        float p1 = __expf(s[kb][2 * t + 1] - m);
        rs += p0 + p1;
        w[kb][t] = pk2(p0, p1);
      }
    rs += __shfl_xor(rs, 32);
    lsum = lsum * fsc + rs;

    if (resc) {  // rescale O: need fsc at q' = crow(r,hi); broadcast via per-warp LDS row
      if (hi == 0) Lf[wq][ln] = fsc;
#pragma unroll
      for (int rq = 0; rq < 4; ++rq) {
        f32x4 fv = *(const f32x4*)&Lf[wq][rq * 8 + hi * 4];
#pragma unroll
        for (int c = 0; c < 4; ++c) { o0[rq * 4 + c] *= fv[c]; o1[rq * 4 + c] *= fv[c]; }
      }
    }

    // PV: rebuild P A-fragments in-register (pack bf16 + cross-hi shfl), then mfma(P, V)
    const char* vb_base = (const char*)vbuf[cur];
#pragma unroll
    for (int ks = 0; ks < 4; ++ks) {
      const int kb = ks >> 1, i0 = (ks & 1) * 4;
      u32 sA = hi ? w[kb][i0 + 0] : w[kb][i0 + 2];
      u32 sB = hi ? w[kb][i0 + 1] : w[kb][i0 + 3];
      u32 rA = (u32)__shfl_xor((int)sA, 32);
      u32 rB = (u32)__shfl_xor((int)sB, 32);
      u32 e0 = hi ? rA : w[kb][i0 + 0];
      u32 e1 = hi ? rB : w[kb][i0 + 1];
      u32 e2 = hi ? w[kb][i0 + 2] : rA;
      u32 e3 = hi ? w[kb][i0 + 3] : rB;
      union { u32x4 u; bf16x8 v; } pc;
      pc.u = (u32x4){e0, e1, e2, e3};
      bf16x8 pa = pc.v;
#pragma unroll
      for (int nv = 0; nv < 2; ++nv) {
        bf16x8 vf = *(const bf16x8*)(vb_base + (nv * 32 + ln) * 128 + (((u32)(ks * 32 + hi * 16)) ^ swz));
        if (nv == 0) o0 = MFMA32(pa, vf, o0);
        else         o1 = MFMA32(pa, vf, o1);
      }
    }

    // write next tile into the other buffer, one barrier per tile
    if (kt < 15) {
      char* kd = (char*)kbuf[cur ^ 1];
      char* vd = (char*)vbuf[cur ^ 1];
      *(u16x8*)(kd + wa0) = kr0;
      *(u16x8*)(kd + wa1) = kr1;
      *(u16x8*)(vd + wa0) = vr0;
      *(u16x8*)(vd + wa1) = vr1;
      __syncthreads();
      cur ^= 1;
    }
  }

  // epilogue: gather 1/l at q' = crow(r,hi) via per-warp LDS row, write O (bf16)
  float inv = 1.0f / lsum;
  if (hi == 0) Lf[wq][ln] = inv;
#pragma unroll
  for (int rq = 0; rq < 4; ++rq) {
    f32x4 iv = *(const f32x4*)&Lf[wq][rq * 8 + hi * 4];
#pragma unroll
    for (int c = 0; c < 4; ++c) {
      int q = q0 + wq * 32 + rq * 8 + hi * 4 + c;
      u16* op = O + (size_t)(b * SS + q) * DD + h * 64 + ln;
      op[0]  = f2b(o0[rq * 4 + c] * iv[c]);
      op[32] = f2b(o1[rq * 4 + c] * iv[c]);
    }
  }
}

// ---------------- host launch ----------------
extern "C" void kernel_launch(void* const* d_in, const int* in_sizes, int n_in,
                              void* d_out, int out_size, void* d_ws, size_t ws_size,
                              hipStream_t stream) {
  const float* queries = (const float*)d_in[0];
  const float* keys    = (const float*)d_in[1];
  const float* values  = (const float*)d_in[2];
  const float* bias    = (const float*)d_in[3];
  const float* Wq      = (const float*)d_in[4];
  const float* Wk      = (const float*)d_in[5];
  const float* Wv      = (const float*)d_in[6];
  const float* Wp      = (const float*)d_in[7];
  float* out = (float*)d_out;

  char* ws = (char*)d_ws;
  const size_t MB = 1024 * 1024;
  u16* qb  = (u16*)(ws + 0 * MB);
  u16* kb  = (u16*)(ws + 8 * MB);
  u16* vb  = (u16*)(ws + 16 * MB);
  u16* wqb = (u16*)(ws + 24 * MB);
  u16* wkb = (u16*)(ws + 26 * MB);
  u16* wvb = (u16*)(ws + 28 * MB);
  u16* wpb = (u16*)(ws + 30 * MB);
  u16* Qb  = (u16*)(ws + 32 * MB);
  u16* Kb  = (u16*)(ws + 40 * MB);
  u16* Vb  = (u16*)(ws + 48 * MB);
  u16* Vtb = (u16*)(ws + 56 * MB);
  u16* Ob  = (u16*)(ws + 0 * MB);  // reuse qb region (dead after projections)

  const int nAct = BB * SS * DD;  // 4M
  const int nW = DD * DD;         // 1M

  cvt_all<<<dim3(16384), dim3(256), 0, stream>>>(
      queries, keys, values, Wq, Wk, Wv, Wp,
      qb, kb, vb, wqb, wkb, wvb, wpb);

  gemm_bt<u16><<<dim3(8, 32, 3), dim3(256), 0, stream>>>(
      qb, wqb, Qb, DD, DD, (size_t)nAct, (size_t)nW, (size_t)nAct);

  transpose_v<<<dim3(16, 16, 4), dim3(256), 0, stream>>>(Vb, Vtb);

  attn_kernel<<<dim3(8, 16, 4), dim3(256), 0, stream>>>(Qb, Kb, Vtb, bias, Ob);

  gemm_bt<float><<<dim3(8, 32, 1), dim3(256), 0, stream>>>(
      Ob, wpb, out, DD, DD, 0, 0, 0);
}